// Round 13
// baseline (146.440 us; speedup 1.0000x reference)
//
#include <hip/hip_runtime.h>
#include <hip/hip_bf16.h>

#define S_LEN 2048
#define D_MODEL 2048
#define NH 16
#define NKVH 4
#define HD 128
#define KVB 64
#define EPS_STRIDE 132   // epilogue LDS row stride (f32), 4-aligned, non-pow2

typedef __attribute__((ext_vector_type(8))) short bh8;   // 8 bf16
typedef __attribute__((ext_vector_type(4))) short bh4;   // 4 bf16
typedef __attribute__((ext_vector_type(4))) float f4;
typedef unsigned short u16;
typedef unsigned int u32;

#define GAS __attribute__((address_space(1)))
#define LAS __attribute__((address_space(3)))

__device__ __forceinline__ u16 bf16u(float x) {
    __hip_bfloat16 h = __float2bfloat16(x);
    return __builtin_bit_cast(u16, h);
}
__device__ __forceinline__ float b2f(u16 u) {
    return __builtin_bit_cast(float, (u32)u << 16);
}
__device__ __forceinline__ u32 pack2(float a, float b) {
    return (u32)bf16u(a) | ((u32)bf16u(b) << 16);
}

// Hardened barrier: explicit drain of async global_load_lds + LDS ops, fenced
// against compiler reordering (rule #18), then the block barrier.
#define SYNC_FULL()                                                      \
    do {                                                                 \
        asm volatile("s_waitcnt vmcnt(0) lgkmcnt(0)" ::: "memory");      \
        __builtin_amdgcn_sched_barrier(0);                               \
        __syncthreads();                                                 \
    } while (0)

// ---------------- fused fp32 -> bf16 conversion (4 regions, 1 launch) --------
__device__ __forceinline__ void cvt_region(const float* __restrict__ in,
                                           u16* __restrict__ out, int n,
                                           int gtid, int gthreads) {
    for (int i = gtid * 4; i < n; i += gthreads * 4) {
        float4 v = *reinterpret_cast<const float4*>(in + i);
        ushort4 o;
        o.x = bf16u(v.x); o.y = bf16u(v.y); o.z = bf16u(v.z); o.w = bf16u(v.w);
        *reinterpret_cast<ushort4*>(out + i) = o;
    }
}
__global__ __launch_bounds__(256) void cvt_all(const float* __restrict__ a, u16* __restrict__ oa, int na,
                                               const float* __restrict__ b, u16* __restrict__ ob, int nb,
                                               const float* __restrict__ c, u16* __restrict__ oc, int nc,
                                               const float* __restrict__ d, u16* __restrict__ od, int nd) {
    int gtid = blockIdx.x * 256 + threadIdx.x;
    int gthreads = gridDim.x * 256;
    cvt_region(a, oa, na, gtid, gthreads);
    cvt_region(b, ob, nb, gtid, gthreads);
    cvt_region(c, oc, nc, gtid, gthreads);
    cvt_region(d, od, nd, gtid, gthreads);
}

// ---------------- V transpose: VT[h][d][t] = V[h][t][d], bf16 ----------------
__global__ __launch_bounds__(256) void transpose_v(const float* __restrict__ V,
                                                   u16* __restrict__ VT) {
    __shared__ float tile[32][33];
    int h = blockIdx.z;
    int t0 = blockIdx.x * 32, d0 = blockIdx.y * 32;
    int tx = threadIdx.x & 31, ty = threadIdx.x >> 5;
#pragma unroll
    for (int r = 0; r < 4; ++r) {
        int t = ty + r * 8;
        tile[t][tx] = V[(size_t)h * S_LEN * HD + (size_t)(t0 + t) * HD + d0 + tx];
    }
    __syncthreads();
#pragma unroll
    for (int r = 0; r < 4; ++r) {
        int d = ty + r * 8;
        VT[(size_t)h * HD * S_LEN + (size_t)(d0 + d) * S_LEN + t0 + tx] = bf16u(tile[tx][d]);
    }
}

// -------- bf16 NT GEMM, 128x128, BK=64, dbuf, XOR-swizzled LDS ---------------
template<typename OT>
__global__ __launch_bounds__(256) void gemm_nt(const u16* __restrict__ A,
                                               const u16* __restrict__ B,
                                               OT* __restrict__ C,
                                               int M, int N, int K) {
    __shared__ u16 As[2][128 * 64];
    __shared__ u16 Bs[2][128 * 64];
    const int tid = threadIdx.x;
    const int wid = tid >> 6, lane = tid & 63;

    const int gx = gridDim.x, gy = gridDim.y;
    int tx = blockIdx.x, ty = blockIdx.y;
    {
        int total = gx * gy;
        if ((total & 63) == 0 && gx >= 8) {
            int chunk = total >> 3;
            int srows = chunk >> 3;
            if (srows > 0 && (gy % srows) == 0) {
                int bid = blockIdx.y * gx + blockIdx.x;
                int xcd = bid & 7, loc = bid >> 3;
                int nsx = gx >> 3;
                int sqx = xcd % nsx, sqy = xcd / nsx;
                tx = sqx * 8 + (loc & 7);
                ty = sqy * srows + (loc >> 3);
            }
        }
    }
    const int row0 = ty * 128, col0 = tx * 128;
    const int wr = (wid >> 1) * 64, wc = (wid & 1) * 64;

    f4 acc[4][4] = {};
    const int fr = lane & 15, hi4 = lane >> 4;
    const int sx = fr & 7;

#define GSTAGE(b, k0)                                                             \
    {                                                                             \
        _Pragma("unroll")                                                         \
        for (int i = 0; i < 4; ++i) {                                             \
            int rb = i * 32 + wid * 8;                                            \
            int row = rb + (lane >> 3);                                           \
            int ck = (lane & 7) ^ (lane >> 3);                                    \
            __builtin_amdgcn_global_load_lds(                                     \
                (const GAS void*)(A + (size_t)(row0 + row) * K + (k0) + ck * 8),  \
                (LAS void*)(As[b] + rb * 64), 16, 0, 0);                          \
            __builtin_amdgcn_global_load_lds(                                     \
                (const GAS void*)(B + (size_t)(col0 + row) * K + (k0) + ck * 8),  \
                (LAS void*)(Bs[b] + rb * 64), 16, 0, 0);                          \
        }                                                                         \
    }

    GSTAGE(0, 0);
    __syncthreads();

    const int nk = K >> 6;
    for (int t = 0; t < nk; ++t) {
        const int cur = t & 1;
        if (t + 1 < nk) GSTAGE(cur ^ 1, (t + 1) * 64);

#pragma unroll
        for (int kb = 0; kb < 2; ++kb) {
            const int ca = ((kb * 4 + hi4) ^ sx) * 8;
            bh8 af[4], bfv[4];
#pragma unroll
            for (int i = 0; i < 4; ++i) {
                af[i]  = *reinterpret_cast<const bh8*>(&As[cur][(wr + i * 16 + fr) * 64 + ca]);
                bfv[i] = *reinterpret_cast<const bh8*>(&Bs[cur][(wc + i * 16 + fr) * 64 + ca]);
            }
#pragma unroll
            for (int i = 0; i < 4; ++i)
#pragma unroll
                for (int j = 0; j < 4; ++j)
                    acc[i][j] = __builtin_amdgcn_mfma_f32_16x16x32_bf16(af[i], bfv[j], acc[i][j], 0, 0, 0);
        }
        __syncthreads();
    }
#undef GSTAGE

    const int orow = hi4 * 4, ocol = fr;
#pragma unroll
    for (int i = 0; i < 4; ++i)
#pragma unroll
        for (int j = 0; j < 4; ++j)
#pragma unroll
            for (int e = 0; e < 4; ++e) {
                float v = acc[i][j][e];
                size_t off = (size_t)(row0 + wr + i * 16 + orow + e) * N + col0 + wc + j * 16 + ocol;
                if constexpr (__is_same(OT, u16)) C[off] = bf16u(v);
                else C[off] = v;
            }
}

// -------- bf16 NT GEMM, 128x64, BK=64, dbuf, XOR-swizzled LDS ----------------
template<typename OT>
__global__ __launch_bounds__(256) void gemm_nt64(const u16* __restrict__ A,
                                                 const u16* __restrict__ B,
                                                 OT* __restrict__ C,
                                                 int M, int N, int K) {
    __shared__ u16 As[2][128 * 64];
    __shared__ u16 Bs[2][64 * 64];
    const int tid = threadIdx.x;
    const int wid = tid >> 6, lane = tid & 63;

    const int gx = gridDim.x, gy = gridDim.y;
    int tx = blockIdx.x, ty = blockIdx.y;
    {
        int total = gx * gy;
        if ((total & 63) == 0 && gx >= 8) {
            int chunk = total >> 3;
            int srows = chunk >> 3;
            if (srows > 0 && (gy % srows) == 0) {
                int bid = blockIdx.y * gx + blockIdx.x;
                int xcd = bid & 7, loc = bid >> 3;
                int nsx = gx >> 3;
                int sqx = xcd % nsx, sqy = xcd / nsx;
                tx = sqx * 8 + (loc & 7);
                ty = sqy * srows + (loc >> 3);
            }
        }
    }
    const int row0 = ty * 128, col0 = tx * 64;
    const int wr = (wid >> 1) * 64, wc = (wid & 1) * 32;

    f4 acc[4][2] = {};
    const int fr = lane & 15, hi4 = lane >> 4;
    const int sx = fr & 7;

#define GSTAGE64(b, k0)                                                           \
    {                                                                             \
        _Pragma("unroll")                                                         \
        for (int i = 0; i < 4; ++i) {                                             \
            int rb = i * 32 + wid * 8;                                            \
            int row = rb + (lane >> 3);                                           \
            int ck = (lane & 7) ^ (lane >> 3);                                    \
            __builtin_amdgcn_global_load_lds(                                     \
                (const GAS void*)(A + (size_t)(row0 + row) * K + (k0) + ck * 8),  \
                (LAS void*)(As[b] + rb * 64), 16, 0, 0);                          \
        }                                                                         \
        _Pragma("unroll")                                                         \
        for (int i = 0; i < 2; ++i) {                                             \
            int rb = wid * 16 + i * 8;                                            \
            int row = rb + (lane >> 3);                                           \
            int ck = (lane & 7) ^ (lane >> 3);                                    \
            __builtin_amdgcn_global_load_lds(                                     \
                (const GAS void*)(B + (size_t)(col0 + row) * K + (k0) + ck * 8),  \
                (LAS void*)(Bs[b] + rb * 64), 16, 0, 0);                          \
        }                                                                         \
    }

    GSTAGE64(0, 0);
    __syncthreads();

    const int nk = K >> 6;
    for (int t = 0; t < nk; ++t) {
        const int cur = t & 1;
        if (t + 1 < nk) GSTAGE64(cur ^ 1, (t + 1) * 64);

#pragma unroll
        for (int kb = 0; kb < 2; ++kb) {
            const int ca = ((kb * 4 + hi4) ^ sx) * 8;
            bh8 af[4], bfv[2];
#pragma unroll
            for (int i = 0; i < 4; ++i)
                af[i] = *reinterpret_cast<const bh8*>(&As[cur][(wr + i * 16 + fr) * 64 + ca]);
#pragma unroll
            for (int j = 0; j < 2; ++j)
                bfv[j] = *reinterpret_cast<const bh8*>(&Bs[cur][(wc + j * 16 + fr) * 64 + ca]);
#pragma unroll
            for (int i = 0; i < 4; ++i)
#pragma unroll
                for (int j = 0; j < 2; ++j)
                    acc[i][j] = __builtin_amdgcn_mfma_f32_16x16x32_bf16(af[i], bfv[j], acc[i][j], 0, 0, 0);
        }
        __syncthreads();
    }
#undef GSTAGE64

    const int orow = hi4 * 4, ocol = fr;
#pragma unroll
    for (int i = 0; i < 4; ++i)
#pragma unroll
        for (int j = 0; j < 2; ++j)
#pragma unroll
            for (int e = 0; e < 4; ++e) {
                float v = acc[i][j][e];
                size_t off = (size_t)(row0 + wr + i * 16 + orow + e) * N + col0 + wc + j * 16 + ocol;
                if constexpr (__is_same(OT, u16)) C[off] = bf16u(v);
                else C[off] = v;
            }
}

// ---------------- q prep: RMS + partial RoPE + fold SCALE*log2e, bf16 --------
__global__ __launch_bounds__(256) void qprep(const u16* __restrict__ C1b,
                                             const float* __restrict__ cosb,
                                             const float* __restrict__ sinb,
                                             const float* __restrict__ qw,
                                             u16* __restrict__ Qb) {
    constexpr float KS = 0.08838834764831845f * 1.4426950408889634f;
    int wid = threadIdx.x >> 6, lane = threadIdx.x & 63;
    int id = blockIdx.x * 4 + wid;          // (h,s) index
    int h = id >> 11, s = id & 2047;
    const u16* row = C1b + (size_t)s * 4096 + h * 256;
    float v0 = b2f(row[lane]), v1 = b2f(row[lane + 64]);
    float ss = v0 * v0 + v1 * v1;
#pragma unroll
    for (int off = 32; off; off >>= 1) ss += __shfl_xor(ss, off, 64);
    float sc = rsqrtf(ss * (1.f / 128.f) + 1e-6f);
    float q0 = v0 * sc * (1.f + qw[lane]);
    float q1 = v1 * sc * (1.f + qw[lane + 64]);
    float part = __shfl_xor(q0, 32, 64);
    float rot = (lane < 32) ? -part : part;
    float c = cosb[s * 64 + lane], sn = sinb[s * 64 + lane];
    float o0 = q0 * c + rot * sn;
    u16* dst = Qb + (size_t)h * S_LEN * HD + (size_t)s * HD;
    dst[lane] = bf16u(o0 * KS);
    dst[lane + 64] = bf16u(q1 * KS);
}

// ------- flash attention, swapped-QK, 32 q-rows/wave, 4-way KV split ---------
// Job = (h, 128 q-rows, quad j): tiles t = j, j+4, ... < 2qb+2. 1024 jobs,
// LPT order, dispatcher backfills. Hardened barriers: explicit vmcnt drain.
__global__ __launch_bounds__(256, 2) void attn_kernel(const u16* __restrict__ Qb,
                                                      const u16* __restrict__ Kb,
                                                      const u16* __restrict__ VTb,
                                                      u16* __restrict__ Oq0,
                                                      u16* __restrict__ Oq1,
                                                      u16* __restrict__ Oq2,
                                                      u16* __restrict__ Oq3,
                                                      float* __restrict__ Mq,
                                                      float* __restrict__ Lq) {
    __shared__ __align__(16) char buf[65536];          // 64 KiB
    u16* Kt0 = (u16*)buf;                              // [64 kv][128 d]
    u16* Vt0 = (u16*)(buf + 16384);                    // [128 d][64 kv]
    u16* Kt1 = (u16*)(buf + 32768);
    u16* Vt1 = (u16*)(buf + 49152);

    const int tid = threadIdx.x, wid = tid >> 6, lane = tid & 63;
    const int bid = blockIdx.x;          // 0..1023, LPT: qb=15 group first
    const int qb = 15 - (bid >> 6);
    const int h = (bid >> 2) & 15;
    const int jq = bid & 3;
    const int q0w = qb * 128 + wid * 32;               // wave's 32 q-rows
    const int h4 = h >> 2;
    const u16* Qh = Qb + (size_t)h * S_LEN * HD;
    const u16* Kh = Kb + (size_t)h4 * S_LEN * HD;
    const u16* Vh = VTb + (size_t)h4 * HD * S_LEN;
    const int fr = lane & 15, hi4 = lane >> 4;
    const int sx = fr & 7;
    constexpr float THR = 11.5f;

    const int T = 2 * qb + 2;            // total KV tiles for this q-block
    const int tmask = q0w >> 6;          // first tile needing causal mask
    const int qrow0 = q0w + fr;
    const int qrow1 = q0w + 16 + fr;

    bh8 qf0[4], qf1[4];
#pragma unroll
    for (int kb = 0; kb < 4; ++kb) {
        qf0[kb] = *reinterpret_cast<const bh8*>(&Qh[(size_t)qrow0 * HD + kb * 32 + hi4 * 8]);
        qf1[kb] = *reinterpret_cast<const bh8*>(&Qh[(size_t)qrow1 * HD + kb * 32 + hi4 * 8]);
    }

    f4 acc0[8] = {}, acc1[8] = {};       // O^T per q-block
    float mr0 = -1e30f, lr0 = 0.f, mr1 = -1e30f, lr1 = 0.f;

#define STAGE(kd, vd, t0)                                                         \
    {                                                                             \
        _Pragma("unroll")                                                         \
        for (int i = 0; i < 4; ++i) {                                             \
            int row = wid * 16 + i * 4 + (lane >> 4);                             \
            int ck = (lane & 15) ^ (row & 7);                                     \
            __builtin_amdgcn_global_load_lds(                                     \
                (const GAS void*)(Kh + (size_t)((t0) + row) * HD + ck * 8),       \
                (LAS void*)((kd) + (wid * 16 + i * 4) * HD), 16, 0, 0);           \
        }                                                                         \
        _Pragma("unroll")                                                         \
        for (int i = 0; i < 4; ++i) {                                             \
            int row = wid * 32 + i * 8 + (lane >> 3);                             \
            int cv = (lane & 7) ^ (row & 7);                                      \
            __builtin_amdgcn_global_load_lds(                                     \
                (const GAS void*)(Vh + (size_t)row * S_LEN + (t0) + cv * 8),      \
                (LAS void*)((vd) + (wid * 32 + i * 8) * KVB), 16, 0, 0);          \
        }                                                                         \
    }

    auto tile_step = [&](int t0, const u16* Ktc, const u16* Vtc, bool masked) {
        f4 z0[4], z1[4];
#pragma unroll
        for (int nf = 0; nf < 4; ++nf) {
            f4 a = {}, b = {};
#pragma unroll
            for (int kb = 0; kb < 4; ++kb) {
                bh8 kf = *reinterpret_cast<const bh8*>(
                    &Ktc[(nf * 16 + fr) * HD + (((kb * 4 + hi4) ^ sx) * 8)]);
                a = __builtin_amdgcn_mfma_f32_16x16x32_bf16(kf, qf0[kb], a, 0, 0, 0);
                b = __builtin_amdgcn_mfma_f32_16x16x32_bf16(kf, qf1[kb], b, 0, 0, 0);
            }
            z0[nf] = a; z1[nf] = b;
        }
        if (masked) {
#pragma unroll
            for (int nf = 0; nf < 4; ++nf)
#pragma unroll
                for (int j = 0; j < 4; ++j) {
                    int kv = t0 + nf * 16 + hi4 * 4 + j;
                    if (kv > qrow0) z0[nf][j] = -3.0e38f;
                    if (kv > qrow1) z1[nf][j] = -3.0e38f;
                }
        }
        float v0 = z0[0][0], v1 = z1[0][0];
#pragma unroll
        for (int nf = 0; nf < 4; ++nf)
#pragma unroll
            for (int j = 0; j < 4; ++j) {
                v0 = fmaxf(v0, z0[nf][j]);
                v1 = fmaxf(v1, z1[nf][j]);
            }
        v0 = fmaxf(v0, __shfl_xor(v0, 16, 64));
        v0 = fmaxf(v0, __shfl_xor(v0, 32, 64));
        v1 = fmaxf(v1, __shfl_xor(v1, 16, 64));
        v1 = fmaxf(v1, __shfl_xor(v1, 32, 64));
        bool need = (v0 > mr0 + THR) || (v1 > mr1 + THR);
        if (__any(need)) {
            float nm0 = fmaxf(mr0, v0), nm1 = fmaxf(mr1, v1);
            float c0 = exp2f(mr0 - nm0), c1 = exp2f(mr1 - nm1);
            mr0 = nm0; mr1 = nm1;
            lr0 *= c0; lr1 *= c1;
#pragma unroll
            for (int dt = 0; dt < 8; ++dt)
#pragma unroll
                for (int j = 0; j < 4; ++j) {
                    acc0[dt][j] *= c0;
                    acc1[dt][j] *= c1;
                }
        }
        u32 pk0[4][2], pk1[4][2];
#pragma unroll
        for (int nf = 0; nf < 4; ++nf) {
            float a0 = exp2f(z0[nf][0] - mr0), a1 = exp2f(z0[nf][1] - mr0);
            float a2 = exp2f(z0[nf][2] - mr0), a3 = exp2f(z0[nf][3] - mr0);
            lr0 += (a0 + a1) + (a2 + a3);
            pk0[nf][0] = pack2(a0, a1);
            pk0[nf][1] = pack2(a2, a3);
            float b0 = exp2f(z1[nf][0] - mr1), b1 = exp2f(z1[nf][1] - mr1);
            float b2 = exp2f(z1[nf][2] - mr1), b3 = exp2f(z1[nf][3] - mr1);
            lr1 += (b0 + b1) + (b2 + b3);
            pk1[nf][0] = pack2(b0, b1);
            pk1[nf][1] = pack2(b2, b3);
        }
#pragma unroll
        for (int kk = 0; kk < 2; ++kk) {
            union { u32 w[4]; bh8 v8; } ua, ub;
            ua.w[0] = pk0[2 * kk][0];     ua.w[1] = pk0[2 * kk][1];
            ua.w[2] = pk0[2 * kk + 1][0]; ua.w[3] = pk0[2 * kk + 1][1];
            ub.w[0] = pk1[2 * kk][0];     ub.w[1] = pk1[2 * kk][1];
            ub.w[2] = pk1[2 * kk + 1][0]; ub.w[3] = pk1[2 * kk + 1][1];
            bh8 pa = ua.v8, pb = ub.v8;
            const int cA = kk * 4 + (hi4 >> 1);
            const int off = (hi4 & 1) * 4;
#pragma unroll
            for (int dt = 0; dt < 8; ++dt) {
                int base = (dt * 16 + fr) * KVB;
                bh4 lo = *reinterpret_cast<const bh4*>(&Vtc[base + ((cA ^ sx) * 8) + off]);
                bh4 hi = *reinterpret_cast<const bh4*>(&Vtc[base + (((cA + 2) ^ sx) * 8) + off]);
                bh8 vf = __builtin_shufflevector(lo, hi, 0, 1, 2, 3, 4, 5, 6, 7);
                acc0[dt] = __builtin_amdgcn_mfma_f32_16x16x32_bf16(vf, pa, acc0[dt], 0, 0, 0);
                acc1[dt] = __builtin_amdgcn_mfma_f32_16x16x32_bf16(vf, pb, acc1[dt], 0, 0, 0);
            }
        }
    };

    if (jq < T) {
        STAGE(Kt0, Vt0, jq * KVB);
        SYNC_FULL();
        int cur = 0;
        for (int t = jq; t < T; t += 4) {
            if (t + 4 < T) {
                if (cur) STAGE(Kt0, Vt0, (t + 4) * KVB)
                else     STAGE(Kt1, Vt1, (t + 4) * KVB)
            }
            tile_step(t * KVB, cur ? Kt1 : Kt0, cur ? Vt1 : Vt0, t >= tmask);
            SYNC_FULL();                 // readers done + async stage drained
            cur ^= 1;
        }
    } else {
        __syncthreads();                 // keep barrier schedule... no shared use
    }
#undef STAGE

    u16* Op = (jq == 0) ? Oq0 : (jq == 1) ? Oq1 : (jq == 2) ? Oq2 : Oq3;
    float* Mp = Mq + jq * (NH * S_LEN);
    float* Lp = Lq + jq * (NH * S_LEN);
    float* ep = (float*)buf + wid * (16 * EPS_STRIDE);
    const int q_l = lane >> 2;           // 0..15
    const int c0 = (lane & 3) * 32;      // d base

#define EPILOG(ACC, MR, LR, ROWOFS)                                               \
    {                                                                             \
        float lt = (LR);                                                          \
        lt += __shfl_xor(lt, 16, 64);                                             \
        lt += __shfl_xor(lt, 32, 64);                                             \
        if (hi4 == 0) {                                                           \
            Mp[h * S_LEN + q0w + (ROWOFS) + fr] = (MR);                           \
            Lp[h * S_LEN + q0w + (ROWOFS) + fr] = lt;                             \
        }                                                                         \
        _Pragma("unroll")                                                         \
        for (int dt = 0; dt < 8; ++dt)                                            \
            _Pragma("unroll")                                                     \
            for (int j = 0; j < 4; ++j)                                           \
                ep[fr * EPS_STRIDE + dt * 16 + hi4 * 4 + j] = ACC[dt][j];         \
        asm volatile("s_waitcnt lgkmcnt(0)" ::: "memory");                        \
        __builtin_amdgcn_sched_barrier(0);                                        \
        {                                                                         \
            const float* eprow = ep + q_l * EPS_STRIDE + c0;                      \
            u16* dst = Op + ((size_t)h * S_LEN + q0w + (ROWOFS) + q_l) * HD + c0; \
            _Pragma("unroll")                                                     \
            for (int i2 = 0; i2 < 4; ++i2) {                                      \
                f4 a = *reinterpret_cast<const f4*>(eprow + i2 * 8);              \
                f4 b = *reinterpret_cast<const f4*>(eprow + i2 * 8 + 4);          \
                uint4 w;                                                          \
                w.x = pack2(a[0], a[1]); w.y = pack2(a[2], a[3]);                 \
                w.z = pack2(b[0], b[1]); w.w = pack2(b[2], b[3]);                 \
                *reinterpret_cast<uint4*>(dst + i2 * 8) = w;                      \
            }                                                                     \
        }                                                                         \
        asm volatile("s_waitcnt lgkmcnt(0)" ::: "memory");                        \
        __builtin_amdgcn_sched_barrier(0);                                        \
    }

    EPILOG(acc0, mr0, lr0, 0);
    EPILOG(acc1, mr1, lr1, 16);
#undef EPILOG
}

// -------- combine: merge 4 KV-quad partials, gate, emit bf16 AO --------------
__global__ __launch_bounds__(256) void attn_combine(const u16* __restrict__ Oq0,
                                                    const u16* __restrict__ Oq1,
                                                    const u16* __restrict__ Oq2,
                                                    const u16* __restrict__ Oq3,
                                                    const float* __restrict__ Mq,
                                                    const float* __restrict__ Lq,
                                                    const u16* __restrict__ C1b,
                                                    u16* __restrict__ AO) {
    constexpr float L2E = 1.4426950408889634f;
    const int NS = NH * S_LEN;
    int idx = blockIdx.x * 256 + threadIdx.x;   // 16*2048*16 total
    int d8 = idx & 15;
    int s  = (idx >> 4) & 2047;
    int h  = idx >> 15;
    int row = h * S_LEN + s;
    float m0 = Mq[row], m1 = Mq[NS + row], m2 = Mq[2 * NS + row], m3 = Mq[3 * NS + row];
    float l0 = Lq[row], l1 = Lq[NS + row], l2 = Lq[2 * NS + row], l3 = Lq[3 * NS + row];
    float m = fmaxf(fmaxf(m0, m1), fmaxf(m2, m3));
    float a = exp2f(m0 - m), b = exp2f(m1 - m), c = exp2f(m2 - m), d = exp2f(m3 - m);
    float inv = 1.f / (a * l0 + b * l1 + c * l2 + d * l3);
    size_t ofs = (size_t)row * HD + d8 * 8;
    bh8 o0 = *reinterpret_cast<const bh8*>(Oq0 + ofs);
    bh8 o1 = *reinterpret_cast<const bh8*>(Oq1 + ofs);
    bh8 o2 = *reinterpret_cast<const bh8*>(Oq2 + ofs);
    bh8 o3 = *reinterpret_cast<const bh8*>(Oq3 + ofs);
    bh8 g  = *reinterpret_cast<const bh8*>(C1b + (size_t)s * 4096 + h * 256 + 128 + d8 * 8);
    u32 w[4];
#pragma unroll
    for (int e = 0; e < 4; ++e) {
        float v0 = (a * b2f((u16)o0[2 * e]) + b * b2f((u16)o1[2 * e]) +
                    c * b2f((u16)o2[2 * e]) + d * b2f((u16)o3[2 * e])) * inv;
        float v1 = (a * b2f((u16)o0[2 * e + 1]) + b * b2f((u16)o1[2 * e + 1]) +
                    c * b2f((u16)o2[2 * e + 1]) + d * b2f((u16)o3[2 * e + 1])) * inv;
        v0 *= 1.f / (1.f + exp2f(-b2f((u16)g[2 * e]) * L2E));
        v1 *= 1.f / (1.f + exp2f(-b2f((u16)g[2 * e + 1]) * L2E));
        w[e] = pack2(v0, v1);
    }
    uint4 ww = {w[0], w[1], w[2], w[3]};
    *reinterpret_cast<uint4*>(AO + (size_t)s * D_MODEL + h * HD + d8 * 8) = ww;
}

extern "C" void kernel_launch(void* const* d_in, const int* in_sizes, int n_in,
                              void* d_out, int out_size, void* d_ws, size_t ws_size,
                              hipStream_t stream) {
    const float* hs   = (const float*)d_in[0];
    const float* Kc   = (const float*)d_in[1];
    const float* Vc   = (const float*)d_in[2];
    const float* cosb = (const float*)d_in[3];
    const float* sinb = (const float*)d_in[4];
    const float* Wq   = (const float*)d_in[6];
    const float* Wo   = (const float*)d_in[9];
    const float* qw   = (const float*)d_in[10];
    float* out = (float*)d_out;

    char* ws = (char*)d_ws;
    u16*   x_bf  = (u16*)ws;                          // 8 MiB  (dead after gemm1)
    u16*   Wq_bf = (u16*)(ws + (8u << 20));           // 16 MiB (dead after gemm1)
    u16*   Wo_bf = (u16*)(ws + (24u << 20));          // 8 MiB  (live till gemm2)
    u16*   K_bf  = (u16*)(ws + (32u << 20));          // 2 MiB
    u16*   VT_bf = (u16*)(ws + (34u << 20));          // 2 MiB
    u16*   C1b   = (u16*)(ws + (36u << 20));          // 16 MiB bf16 (q|gate)
    u16*   Qb    = (u16*)(ws + (68u << 20));          // 8 MiB
    u16*   AO    = (u16*)(ws + (76u << 20));          // 8 MiB
    // attn partials: 3 quads overlay dead x_bf/Wq_bf, 4th + m/l in free space
    u16*   Oq0   = (u16*)ws;                          // 8 MiB
    u16*   Oq1   = (u16*)(ws + (8u << 20));           // 8 MiB
    u16*   Oq2   = (u16*)(ws + (16u << 20));          // 8 MiB
    u16*   Oq3   = (u16*)(ws + (84u << 20));          // 8 MiB
    float* Mq    = (float*)(ws + (92u << 20));        // 4 x 128 KiB
    float* Lq    = Mq + 4 * NH * S_LEN;               // 4 x 128 KiB (to 93 MiB)

    cvt_all<<<2048, 256, 0, stream>>>(hs, x_bf, 2048 * 2048,
                                      Wq, Wq_bf, 4096 * 2048,
                                      Wo, Wo_bf, 2048 * 2048,
                                      Kc, K_bf, NKVH * S_LEN * HD);
    transpose_v<<<dim3(64, 4, NKVH), 256, 0, stream>>>(Vc, VT_bf);

    gemm_nt<u16><<<dim3(32, 16), 256, 0, stream>>>(x_bf, Wq_bf, C1b, 2048, 4096, 2048);
    qprep<<<8192, 256, 0, stream>>>(C1b, cosb, sinb, qw, Qb);
    attn_kernel<<<1024, 256, 0, stream>>>(Qb, K_bf, VT_bf, Oq0, Oq1, Oq2, Oq3, Mq, Lq);
    attn_combine<<<2048, 256, 0, stream>>>(Oq0, Oq1, Oq2, Oq3, Mq, Lq, C1b, AO);
    gemm_nt64<float><<<dim3(32, 16), 256, 0, stream>>>(AO, Wo_bf, out, 2048, 2048, 2048);
}

// Round 14
// 143.163 us; speedup vs baseline: 1.0229x; 1.0229x over previous
//
#include <hip/hip_runtime.h>
#include <hip/hip_bf16.h>

#define S_LEN 2048
#define D_MODEL 2048
#define NH 16
#define NKVH 4
#define HD 128
#define KVB 32
#define EPS_STRIDE 132   // epilogue LDS row stride (f32), 4-aligned, non-pow2

typedef __attribute__((ext_vector_type(8))) short bh8;   // 8 bf16
typedef __attribute__((ext_vector_type(4))) short bh4;   // 4 bf16
typedef __attribute__((ext_vector_type(4))) float f4;
typedef unsigned short u16;
typedef unsigned int u32;

#define GAS __attribute__((address_space(1)))
#define LAS __attribute__((address_space(3)))

__device__ __forceinline__ u16 bf16u(float x) {
    __hip_bfloat16 h = __float2bfloat16(x);
    return __builtin_bit_cast(u16, h);
}
__device__ __forceinline__ float b2f(u16 u) {
    return __builtin_bit_cast(float, (u32)u << 16);
}
__device__ __forceinline__ u32 pack2(float a, float b) {
    return (u32)bf16u(a) | ((u32)bf16u(b) << 16);
}

// Hardened barrier: explicit drain of async global_load_lds + LDS ops, fenced
// against compiler reordering (rule #18), then the block barrier.
#define SYNC_FULL()                                                      \
    do {                                                                 \
        asm volatile("s_waitcnt vmcnt(0) lgkmcnt(0)" ::: "memory");      \
        __builtin_amdgcn_sched_barrier(0);                               \
        __syncthreads();                                                 \
    } while (0)

// ---------------- fused fp32 -> bf16 conversion (4 regions, 1 launch) --------
__device__ __forceinline__ void cvt_region(const float* __restrict__ in,
                                           u16* __restrict__ out, int n,
                                           int gtid, int gthreads) {
    for (int i = gtid * 4; i < n; i += gthreads * 4) {
        float4 v = *reinterpret_cast<const float4*>(in + i);
        ushort4 o;
        o.x = bf16u(v.x); o.y = bf16u(v.y); o.z = bf16u(v.z); o.w = bf16u(v.w);
        *reinterpret_cast<ushort4*>(out + i) = o;
    }
}
__global__ __launch_bounds__(256) void cvt_all(const float* __restrict__ a, u16* __restrict__ oa, int na,
                                               const float* __restrict__ b, u16* __restrict__ ob, int nb,
                                               const float* __restrict__ c, u16* __restrict__ oc, int nc,
                                               const float* __restrict__ d, u16* __restrict__ od, int nd) {
    int gtid = blockIdx.x * 256 + threadIdx.x;
    int gthreads = gridDim.x * 256;
    cvt_region(a, oa, na, gtid, gthreads);
    cvt_region(b, ob, nb, gtid, gthreads);
    cvt_region(c, oc, nc, gtid, gthreads);
    cvt_region(d, od, nd, gtid, gthreads);
}

// ---------------- V transpose: VT[h][d][t] = V[h][t][d], bf16 ----------------
__global__ __launch_bounds__(256) void transpose_v(const float* __restrict__ V,
                                                   u16* __restrict__ VT) {
    __shared__ float tile[32][33];
    int h = blockIdx.z;
    int t0 = blockIdx.x * 32, d0 = blockIdx.y * 32;
    int tx = threadIdx.x & 31, ty = threadIdx.x >> 5;
#pragma unroll
    for (int r = 0; r < 4; ++r) {
        int t = ty + r * 8;
        tile[t][tx] = V[(size_t)h * S_LEN * HD + (size_t)(t0 + t) * HD + d0 + tx];
    }
    __syncthreads();
#pragma unroll
    for (int r = 0; r < 4; ++r) {
        int d = ty + r * 8;
        VT[(size_t)h * HD * S_LEN + (size_t)(d0 + d) * S_LEN + t0 + tx] = bf16u(tile[tx][d]);
    }
}

// -------- bf16 NT GEMM, 128x128, BK=64, dbuf, XOR-swizzled LDS ---------------
template<typename OT>
__global__ __launch_bounds__(256) void gemm_nt(const u16* __restrict__ A,
                                               const u16* __restrict__ B,
                                               OT* __restrict__ C,
                                               int M, int N, int K) {
    __shared__ u16 As[2][128 * 64];
    __shared__ u16 Bs[2][128 * 64];
    const int tid = threadIdx.x;
    const int wid = tid >> 6, lane = tid & 63;

    const int gx = gridDim.x, gy = gridDim.y;
    int tx = blockIdx.x, ty = blockIdx.y;
    {
        int total = gx * gy;
        if ((total & 63) == 0 && gx >= 8) {
            int chunk = total >> 3;
            int srows = chunk >> 3;
            if (srows > 0 && (gy % srows) == 0) {
                int bid = blockIdx.y * gx + blockIdx.x;
                int xcd = bid & 7, loc = bid >> 3;
                int nsx = gx >> 3;
                int sqx = xcd % nsx, sqy = xcd / nsx;
                tx = sqx * 8 + (loc & 7);
                ty = sqy * srows + (loc >> 3);
            }
        }
    }
    const int row0 = ty * 128, col0 = tx * 128;
    const int wr = (wid >> 1) * 64, wc = (wid & 1) * 64;

    f4 acc[4][4] = {};
    const int fr = lane & 15, hi4 = lane >> 4;
    const int sx = fr & 7;

#define GSTAGE(b, k0)                                                             \
    {                                                                             \
        _Pragma("unroll")                                                         \
        for (int i = 0; i < 4; ++i) {                                             \
            int rb = i * 32 + wid * 8;                                            \
            int row = rb + (lane >> 3);                                           \
            int ck = (lane & 7) ^ (lane >> 3);                                    \
            __builtin_amdgcn_global_load_lds(                                     \
                (const GAS void*)(A + (size_t)(row0 + row) * K + (k0) + ck * 8),  \
                (LAS void*)(As[b] + rb * 64), 16, 0, 0);                          \
            __builtin_amdgcn_global_load_lds(                                     \
                (const GAS void*)(B + (size_t)(col0 + row) * K + (k0) + ck * 8),  \
                (LAS void*)(Bs[b] + rb * 64), 16, 0, 0);                          \
        }                                                                         \
    }

    GSTAGE(0, 0);
    __syncthreads();

    const int nk = K >> 6;
    for (int t = 0; t < nk; ++t) {
        const int cur = t & 1;
        if (t + 1 < nk) GSTAGE(cur ^ 1, (t + 1) * 64);

#pragma unroll
        for (int kb = 0; kb < 2; ++kb) {
            const int ca = ((kb * 4 + hi4) ^ sx) * 8;
            bh8 af[4], bfv[4];
#pragma unroll
            for (int i = 0; i < 4; ++i) {
                af[i]  = *reinterpret_cast<const bh8*>(&As[cur][(wr + i * 16 + fr) * 64 + ca]);
                bfv[i] = *reinterpret_cast<const bh8*>(&Bs[cur][(wc + i * 16 + fr) * 64 + ca]);
            }
#pragma unroll
            for (int i = 0; i < 4; ++i)
#pragma unroll
                for (int j = 0; j < 4; ++j)
                    acc[i][j] = __builtin_amdgcn_mfma_f32_16x16x32_bf16(af[i], bfv[j], acc[i][j], 0, 0, 0);
        }
        __syncthreads();
    }
#undef GSTAGE

    const int orow = hi4 * 4, ocol = fr;
#pragma unroll
    for (int i = 0; i < 4; ++i)
#pragma unroll
        for (int j = 0; j < 4; ++j)
#pragma unroll
            for (int e = 0; e < 4; ++e) {
                float v = acc[i][j][e];
                size_t off = (size_t)(row0 + wr + i * 16 + orow + e) * N + col0 + wc + j * 16 + ocol;
                if constexpr (__is_same(OT, u16)) C[off] = bf16u(v);
                else C[off] = v;
            }
}

// -------- bf16 NT GEMM, 128x64, BK=64, dbuf, XOR-swizzled LDS ----------------
template<typename OT>
__global__ __launch_bounds__(256) void gemm_nt64(const u16* __restrict__ A,
                                                 const u16* __restrict__ B,
                                                 OT* __restrict__ C,
                                                 int M, int N, int K) {
    __shared__ u16 As[2][128 * 64];
    __shared__ u16 Bs[2][64 * 64];
    const int tid = threadIdx.x;
    const int wid = tid >> 6, lane = tid & 63;

    const int gx = gridDim.x, gy = gridDim.y;
    int tx = blockIdx.x, ty = blockIdx.y;
    {
        int total = gx * gy;
        if ((total & 63) == 0 && gx >= 8) {
            int chunk = total >> 3;
            int srows = chunk >> 3;
            if (srows > 0 && (gy % srows) == 0) {
                int bid = blockIdx.y * gx + blockIdx.x;
                int xcd = bid & 7, loc = bid >> 3;
                int nsx = gx >> 3;
                int sqx = xcd % nsx, sqy = xcd / nsx;
                tx = sqx * 8 + (loc & 7);
                ty = sqy * srows + (loc >> 3);
            }
        }
    }
    const int row0 = ty * 128, col0 = tx * 64;
    const int wr = (wid >> 1) * 64, wc = (wid & 1) * 32;

    f4 acc[4][2] = {};
    const int fr = lane & 15, hi4 = lane >> 4;
    const int sx = fr & 7;

#define GSTAGE64(b, k0)                                                           \
    {                                                                             \
        _Pragma("unroll")                                                         \
        for (int i = 0; i < 4; ++i) {                                             \
            int rb = i * 32 + wid * 8;                                            \
            int row = rb + (lane >> 3);                                           \
            int ck = (lane & 7) ^ (lane >> 3);                                    \
            __builtin_amdgcn_global_load_lds(                                     \
                (const GAS void*)(A + (size_t)(row0 + row) * K + (k0) + ck * 8),  \
                (LAS void*)(As[b] + rb * 64), 16, 0, 0);                          \
        }                                                                         \
        _Pragma("unroll")                                                         \
        for (int i = 0; i < 2; ++i) {                                             \
            int rb = wid * 16 + i * 8;                                            \
            int row = rb + (lane >> 3);                                           \
            int ck = (lane & 7) ^ (lane >> 3);                                    \
            __builtin_amdgcn_global_load_lds(                                     \
                (const GAS void*)(B + (size_t)(col0 + row) * K + (k0) + ck * 8),  \
                (LAS void*)(Bs[b] + rb * 64), 16, 0, 0);                          \
        }                                                                         \
    }

    GSTAGE64(0, 0);
    __syncthreads();

    const int nk = K >> 6;
    for (int t = 0; t < nk; ++t) {
        const int cur = t & 1;
        if (t + 1 < nk) GSTAGE64(cur ^ 1, (t + 1) * 64);

#pragma unroll
        for (int kb = 0; kb < 2; ++kb) {
            const int ca = ((kb * 4 + hi4) ^ sx) * 8;
            bh8 af[4], bfv[2];
#pragma unroll
            for (int i = 0; i < 4; ++i)
                af[i] = *reinterpret_cast<const bh8*>(&As[cur][(wr + i * 16 + fr) * 64 + ca]);
#pragma unroll
            for (int j = 0; j < 2; ++j)
                bfv[j] = *reinterpret_cast<const bh8*>(&Bs[cur][(wc + j * 16 + fr) * 64 + ca]);
#pragma unroll
            for (int i = 0; i < 4; ++i)
#pragma unroll
                for (int j = 0; j < 2; ++j)
                    acc[i][j] = __builtin_amdgcn_mfma_f32_16x16x32_bf16(af[i], bfv[j], acc[i][j], 0, 0, 0);
        }
        __syncthreads();
    }
#undef GSTAGE64

    const int orow = hi4 * 4, ocol = fr;
#pragma unroll
    for (int i = 0; i < 4; ++i)
#pragma unroll
        for (int j = 0; j < 2; ++j)
#pragma unroll
            for (int e = 0; e < 4; ++e) {
                float v = acc[i][j][e];
                size_t off = (size_t)(row0 + wr + i * 16 + orow + e) * N + col0 + wc + j * 16 + ocol;
                if constexpr (__is_same(OT, u16)) C[off] = bf16u(v);
                else C[off] = v;
            }
}

// ---------------- q prep: RMS + partial RoPE + fold SCALE*log2e, bf16 --------
__global__ __launch_bounds__(256) void qprep(const u16* __restrict__ C1b,
                                             const float* __restrict__ cosb,
                                             const float* __restrict__ sinb,
                                             const float* __restrict__ qw,
                                             u16* __restrict__ Qb) {
    constexpr float KS = 0.08838834764831845f * 1.4426950408889634f;
    int wid = threadIdx.x >> 6, lane = threadIdx.x & 63;
    int id = blockIdx.x * 4 + wid;          // (h,s) index
    int h = id >> 11, s = id & 2047;
    const u16* row = C1b + (size_t)s * 4096 + h * 256;
    float v0 = b2f(row[lane]), v1 = b2f(row[lane + 64]);
    float ss = v0 * v0 + v1 * v1;
#pragma unroll
    for (int off = 32; off; off >>= 1) ss += __shfl_xor(ss, off, 64);
    float sc = rsqrtf(ss * (1.f / 128.f) + 1e-6f);
    float q0 = v0 * sc * (1.f + qw[lane]);
    float q1 = v1 * sc * (1.f + qw[lane + 64]);
    float part = __shfl_xor(q0, 32, 64);
    float rot = (lane < 32) ? -part : part;
    float c = cosb[s * 64 + lane], sn = sinb[s * 64 + lane];
    float o0 = q0 * c + rot * sn;
    u16* dst = Qb + (size_t)h * S_LEN * HD + (size_t)s * HD;
    dst[lane] = bf16u(o0 * KS);
    dst[lane + 64] = bf16u(q1 * KS);
}

// ------- flash attention, swapped-QK, 32 q-rows/wave, 4-way KV split ---------
// KVB=32: staging LDS 32 KB -> higher block residency. Job = (h, 128 q-rows,
// quad j): tiles t = j, j+4, ... < 4qb+4 (each quad gets exactly qb+1 tiles).
__global__ __launch_bounds__(256, 3) void attn_kernel(const u16* __restrict__ Qb,
                                                      const u16* __restrict__ Kb,
                                                      const u16* __restrict__ VTb,
                                                      u16* __restrict__ Oq0,
                                                      u16* __restrict__ Oq1,
                                                      u16* __restrict__ Oq2,
                                                      u16* __restrict__ Oq3,
                                                      float* __restrict__ Mq,
                                                      float* __restrict__ Lq) {
    __shared__ __align__(16) char buf[34048];          // 32 KB staging + epi pad
    u16* Kt0 = (u16*)buf;                              // [32 kv][128 d]  8 KiB
    u16* Vt0 = (u16*)(buf + 8192);                     // [128 d][32 kv]  8 KiB
    u16* Kt1 = (u16*)(buf + 16384);
    u16* Vt1 = (u16*)(buf + 24576);

    const int tid = threadIdx.x, wid = tid >> 6, lane = tid & 63;
    const int bid = blockIdx.x;          // 0..1023, LPT: qb=15 group first
    const int qb = 15 - (bid >> 6);
    const int h = (bid >> 2) & 15;
    const int jq = bid & 3;
    const int q0w = qb * 128 + wid * 32;               // wave's 32 q-rows
    const int h4 = h >> 2;
    const u16* Qh = Qb + (size_t)h * S_LEN * HD;
    const u16* Kh = Kb + (size_t)h4 * S_LEN * HD;
    const u16* Vh = VTb + (size_t)h4 * HD * S_LEN;
    const int fr = lane & 15, hi4 = lane >> 4;
    const int sx = fr & 7;               // K-row chunk swizzle (16 chunks)
    const int sv = (fr >> 1) & 3;        // V-row chunk swizzle (4 chunks)
    constexpr float THR = 11.5f;

    const int T = 4 * qb + 4;            // 32-wide KV tiles for this q-block
    const int tmask = q0w >> 5;          // first tile needing causal mask
    const int qrow0 = q0w + fr;
    const int qrow1 = q0w + 16 + fr;

    bh8 qf0[4], qf1[4];
#pragma unroll
    for (int kb = 0; kb < 4; ++kb) {
        qf0[kb] = *reinterpret_cast<const bh8*>(&Qh[(size_t)qrow0 * HD + kb * 32 + hi4 * 8]);
        qf1[kb] = *reinterpret_cast<const bh8*>(&Qh[(size_t)qrow1 * HD + kb * 32 + hi4 * 8]);
    }

    f4 acc0[8] = {}, acc1[8] = {};       // O^T per q-block
    float mr0 = -1e30f, lr0 = 0.f, mr1 = -1e30f, lr1 = 0.f;

    // K: [32][128] rows, 16 chunks/row, swz ck = c ^ (row&7)
    // V: [128][32] rows, 4 chunks/row,  swz cv = c ^ ((row>>1)&3)
#define STAGE(kd, vd, t0)                                                         \
    {                                                                             \
        _Pragma("unroll")                                                         \
        for (int i = 0; i < 2; ++i) {                                             \
            int row = wid * 8 + i * 4 + (lane >> 4);                              \
            int ck = (lane & 15) ^ (row & 7);                                     \
            __builtin_amdgcn_global_load_lds(                                     \
                (const GAS void*)(Kh + (size_t)((t0) + row) * HD + ck * 8),       \
                (LAS void*)((kd) + (wid * 8 + i * 4) * HD), 16, 0, 0);            \
        }                                                                         \
        _Pragma("unroll")                                                         \
        for (int i = 0; i < 2; ++i) {                                             \
            int row = wid * 32 + i * 16 + (lane >> 2);                            \
            int cv = (lane & 3) ^ ((row >> 1) & 3);                               \
            __builtin_amdgcn_global_load_lds(                                     \
                (const GAS void*)(Vh + (size_t)row * S_LEN + (t0) + cv * 8),      \
                (LAS void*)((vd) + (wid * 32 + i * 16) * KVB), 16, 0, 0);         \
        }                                                                         \
    }

    auto tile_step = [&](int t0, const u16* Ktc, const u16* Vtc, bool masked) {
        f4 z0[2], z1[2];
#pragma unroll
        for (int nf = 0; nf < 2; ++nf) {
            f4 a = {}, b = {};
#pragma unroll
            for (int kb = 0; kb < 4; ++kb) {
                bh8 kf = *reinterpret_cast<const bh8*>(
                    &Ktc[(nf * 16 + fr) * HD + (((kb * 4 + hi4) ^ sx) * 8)]);
                a = __builtin_amdgcn_mfma_f32_16x16x32_bf16(kf, qf0[kb], a, 0, 0, 0);
                b = __builtin_amdgcn_mfma_f32_16x16x32_bf16(kf, qf1[kb], b, 0, 0, 0);
            }
            z0[nf] = a; z1[nf] = b;
        }
        if (masked) {
#pragma unroll
            for (int nf = 0; nf < 2; ++nf)
#pragma unroll
                for (int j = 0; j < 4; ++j) {
                    int kv = t0 + nf * 16 + hi4 * 4 + j;
                    if (kv > qrow0) z0[nf][j] = -3.0e38f;
                    if (kv > qrow1) z1[nf][j] = -3.0e38f;
                }
        }
        float v0 = z0[0][0], v1 = z1[0][0];
#pragma unroll
        for (int nf = 0; nf < 2; ++nf)
#pragma unroll
            for (int j = 0; j < 4; ++j) {
                v0 = fmaxf(v0, z0[nf][j]);
                v1 = fmaxf(v1, z1[nf][j]);
            }
        v0 = fmaxf(v0, __shfl_xor(v0, 16, 64));
        v0 = fmaxf(v0, __shfl_xor(v0, 32, 64));
        v1 = fmaxf(v1, __shfl_xor(v1, 16, 64));
        v1 = fmaxf(v1, __shfl_xor(v1, 32, 64));
        bool need = (v0 > mr0 + THR) || (v1 > mr1 + THR);
        if (__any(need)) {
            float nm0 = fmaxf(mr0, v0), nm1 = fmaxf(mr1, v1);
            float c0 = exp2f(mr0 - nm0), c1 = exp2f(mr1 - nm1);
            mr0 = nm0; mr1 = nm1;
            lr0 *= c0; lr1 *= c1;
#pragma unroll
            for (int dt = 0; dt < 8; ++dt)
#pragma unroll
                for (int j = 0; j < 4; ++j) {
                    acc0[dt][j] *= c0;
                    acc1[dt][j] *= c1;
                }
        }
        u32 pk0[2][2], pk1[2][2];
#pragma unroll
        for (int nf = 0; nf < 2; ++nf) {
            float a0 = exp2f(z0[nf][0] - mr0), a1 = exp2f(z0[nf][1] - mr0);
            float a2 = exp2f(z0[nf][2] - mr0), a3 = exp2f(z0[nf][3] - mr0);
            lr0 += (a0 + a1) + (a2 + a3);
            pk0[nf][0] = pack2(a0, a1);
            pk0[nf][1] = pack2(a2, a3);
            float b0 = exp2f(z1[nf][0] - mr1), b1 = exp2f(z1[nf][1] - mr1);
            float b2 = exp2f(z1[nf][2] - mr1), b3 = exp2f(z1[nf][3] - mr1);
            lr1 += (b0 + b1) + (b2 + b3);
            pk1[nf][0] = pack2(b0, b1);
            pk1[nf][1] = pack2(b2, b3);
        }
        // PV: pa = lane's 8 p-values (kv_map = (e>>2)*16 + hi4*4 + (e&3));
        // V reads sigma-permuted: lo chunk = (hi4>>1)^sv, hi chunk = ((hi4>>1)+2)^sv
        union { u32 w[4]; bh8 v8; } ua, ub;
        ua.w[0] = pk0[0][0]; ua.w[1] = pk0[0][1];
        ua.w[2] = pk0[1][0]; ua.w[3] = pk0[1][1];
        ub.w[0] = pk1[0][0]; ub.w[1] = pk1[0][1];
        ub.w[2] = pk1[1][0]; ub.w[3] = pk1[1][1];
        bh8 pa = ua.v8, pb = ub.v8;
        const int cA = hi4 >> 1;
        const int off = (hi4 & 1) * 4;
#pragma unroll
        for (int dt = 0; dt < 8; ++dt) {
            int base = (dt * 16 + fr) * KVB;
            bh4 lo = *reinterpret_cast<const bh4*>(&Vtc[base + ((cA ^ sv) * 8) + off]);
            bh4 hi = *reinterpret_cast<const bh4*>(&Vtc[base + (((cA + 2) ^ sv) * 8) + off]);
            bh8 vf = __builtin_shufflevector(lo, hi, 0, 1, 2, 3, 4, 5, 6, 7);
            acc0[dt] = __builtin_amdgcn_mfma_f32_16x16x32_bf16(vf, pa, acc0[dt], 0, 0, 0);
            acc1[dt] = __builtin_amdgcn_mfma_f32_16x16x32_bf16(vf, pb, acc1[dt], 0, 0, 0);
        }
    };

    {
        STAGE(Kt0, Vt0, jq * KVB);
        SYNC_FULL();
        int cur = 0;
        for (int t = jq; t < T; t += 4) {
            if (t + 4 < T) {
                if (cur) STAGE(Kt0, Vt0, (t + 4) * KVB)
                else     STAGE(Kt1, Vt1, (t + 4) * KVB)
            }
            tile_step(t * KVB, cur ? Kt1 : Kt0, cur ? Vt1 : Vt0, t >= tmask);
            SYNC_FULL();                 // readers done + async stage drained
            cur ^= 1;
        }
    }
#undef STAGE

    u16* Op = (jq == 0) ? Oq0 : (jq == 1) ? Oq1 : (jq == 2) ? Oq2 : Oq3;
    float* Mp = Mq + jq * (NH * S_LEN);
    float* Lp = Lq + jq * (NH * S_LEN);
    float* ep = (float*)buf + wid * (16 * EPS_STRIDE);
    const int q_l = lane >> 2;           // 0..15
    const int c0 = (lane & 3) * 32;      // d base

#define EPILOG(ACC, MR, LR, ROWOFS)                                               \
    {                                                                             \
        float lt = (LR);                                                          \
        lt += __shfl_xor(lt, 16, 64);                                             \
        lt += __shfl_xor(lt, 32, 64);                                             \
        if (hi4 == 0) {                                                           \
            Mp[h * S_LEN + q0w + (ROWOFS) + fr] = (MR);                           \
            Lp[h * S_LEN + q0w + (ROWOFS) + fr] = lt;                             \
        }                                                                         \
        _Pragma("unroll")                                                         \
        for (int dt = 0; dt < 8; ++dt)                                            \
            _Pragma("unroll")                                                     \
            for (int j = 0; j < 4; ++j)                                           \
                ep[fr * EPS_STRIDE + dt * 16 + hi4 * 4 + j] = ACC[dt][j];         \
        asm volatile("s_waitcnt lgkmcnt(0)" ::: "memory");                        \
        __builtin_amdgcn_sched_barrier(0);                                        \
        {                                                                         \
            const float* eprow = ep + q_l * EPS_STRIDE + c0;                      \
            u16* dst = Op + ((size_t)h * S_LEN + q0w + (ROWOFS) + q_l) * HD + c0; \
            _Pragma("unroll")                                                     \
            for (int i2 = 0; i2 < 4; ++i2) {                                      \
                f4 a = *reinterpret_cast<const f4*>(eprow + i2 * 8);              \
                f4 b = *reinterpret_cast<const f4*>(eprow + i2 * 8 + 4);          \
                uint4 w;                                                          \
                w.x = pack2(a[0], a[1]); w.y = pack2(a[2], a[3]);                 \
                w.z = pack2(b[0], b[1]); w.w = pack2(b[2], b[3]);                 \
                *reinterpret_cast<uint4*>(dst + i2 * 8) = w;                      \
            }                                                                     \
        }                                                                         \
        asm volatile("s_waitcnt lgkmcnt(0)" ::: "memory");                        \
        __builtin_amdgcn_sched_barrier(0);                                        \
    }

    EPILOG(acc0, mr0, lr0, 0);
    EPILOG(acc1, mr1, lr1, 16);
#undef EPILOG
}

// -------- combine: merge 4 KV-quad partials, gate, emit bf16 AO --------------
__global__ __launch_bounds__(256) void attn_combine(const u16* __restrict__ Oq0,
                                                    const u16* __restrict__ Oq1,
                                                    const u16* __restrict__ Oq2,
                                                    const u16* __restrict__ Oq3,
                                                    const float* __restrict__ Mq,
                                                    const float* __restrict__ Lq,
                                                    const u16* __restrict__ C1b,
                                                    u16* __restrict__ AO) {
    constexpr float L2E = 1.4426950408889634f;
    const int NS = NH * S_LEN;
    int idx = blockIdx.x * 256 + threadIdx.x;   // 16*2048*16 total
    int d8 = idx & 15;
    int s  = (idx >> 4) & 2047;
    int h  = idx >> 15;
    int row = h * S_LEN + s;
    float m0 = Mq[row], m1 = Mq[NS + row], m2 = Mq[2 * NS + row], m3 = Mq[3 * NS + row];
    float l0 = Lq[row], l1 = Lq[NS + row], l2 = Lq[2 * NS + row], l3 = Lq[3 * NS + row];
    float m = fmaxf(fmaxf(m0, m1), fmaxf(m2, m3));
    float a = exp2f(m0 - m), b = exp2f(m1 - m), c = exp2f(m2 - m), d = exp2f(m3 - m);
    float inv = 1.f / (a * l0 + b * l1 + c * l2 + d * l3);
    size_t ofs = (size_t)row * HD + d8 * 8;
    bh8 o0 = *reinterpret_cast<const bh8*>(Oq0 + ofs);
    bh8 o1 = *reinterpret_cast<const bh8*>(Oq1 + ofs);
    bh8 o2 = *reinterpret_cast<const bh8*>(Oq2 + ofs);
    bh8 o3 = *reinterpret_cast<const bh8*>(Oq3 + ofs);
    bh8 g  = *reinterpret_cast<const bh8*>(C1b + (size_t)s * 4096 + h * 256 + 128 + d8 * 8);
    u32 w[4];
#pragma unroll
    for (int e = 0; e < 4; ++e) {
        float v0 = (a * b2f((u16)o0[2 * e]) + b * b2f((u16)o1[2 * e]) +
                    c * b2f((u16)o2[2 * e]) + d * b2f((u16)o3[2 * e])) * inv;
        float v1 = (a * b2f((u16)o0[2 * e + 1]) + b * b2f((u16)o1[2 * e + 1]) +
                    c * b2f((u16)o2[2 * e + 1]) + d * b2f((u16)o3[2 * e + 1])) * inv;
        v0 *= 1.f / (1.f + exp2f(-b2f((u16)g[2 * e]) * L2E));
        v1 *= 1.f / (1.f + exp2f(-b2f((u16)g[2 * e + 1]) * L2E));
        w[e] = pack2(v0, v1);
    }
    uint4 ww = {w[0], w[1], w[2], w[3]};
    *reinterpret_cast<uint4*>(AO + (size_t)s * D_MODEL + h * HD + d8 * 8) = ww;
}

extern "C" void kernel_launch(void* const* d_in, const int* in_sizes, int n_in,
                              void* d_out, int out_size, void* d_ws, size_t ws_size,
                              hipStream_t stream) {
    const float* hs   = (const float*)d_in[0];
    const float* Kc   = (const float*)d_in[1];
    const float* Vc   = (const float*)d_in[2];
    const float* cosb = (const float*)d_in[3];
    const float* sinb = (const float*)d_in[4];
    const float* Wq   = (const float*)d_in[6];
    const float* Wo   = (const float*)d_in[9];
    const float* qw   = (const float*)d_in[10];
    float* out = (float*)d_out;

    char* ws = (char*)d_ws;
    u16*   x_bf  = (u16*)ws;                          // 8 MiB  (dead after gemm1)
    u16*   Wq_bf = (u16*)(ws + (8u << 20));           // 16 MiB (dead after gemm1)
    u16*   Wo_bf = (u16*)(ws + (24u << 20));          // 8 MiB  (live till gemm2)
    u16*   K_bf  = (u16*)(ws + (32u << 20));          // 2 MiB
    u16*   VT_bf = (u16*)(ws + (34u << 20));          // 2 MiB
    u16*   C1b   = (u16*)(ws + (36u << 20));          // 16 MiB bf16 (q|gate)
    u16*   Qb    = (u16*)(ws + (68u << 20));          // 8 MiB
    u16*   AO    = (u16*)(ws + (76u << 20));          // 8 MiB
    // attn partials: 3 quads overlay dead x_bf/Wq_bf, 4th + m/l in free space
    u16*   Oq0   = (u16*)ws;                          // 8 MiB
    u16*   Oq1   = (u16*)(ws + (8u << 20));           // 8 MiB
    u16*   Oq2   = (u16*)(ws + (16u << 20));          // 8 MiB
    u16*   Oq3   = (u16*)(ws + (84u << 20));          // 8 MiB
    float* Mq    = (float*)(ws + (92u << 20));        // 4 x 128 KiB
    float* Lq    = Mq + 4 * NH * S_LEN;               // 4 x 128 KiB (to 93 MiB)

    cvt_all<<<2048, 256, 0, stream>>>(hs, x_bf, 2048 * 2048,
                                      Wq, Wq_bf, 4096 * 2048,
                                      Wo, Wo_bf, 2048 * 2048,
                                      Kc, K_bf, NKVH * S_LEN * HD);
    transpose_v<<<dim3(64, 4, NKVH), 256, 0, stream>>>(Vc, VT_bf);

    gemm_nt<u16><<<dim3(32, 16), 256, 0, stream>>>(x_bf, Wq_bf, C1b, 2048, 4096, 2048);
    qprep<<<8192, 256, 0, stream>>>(C1b, cosb, sinb, qw, Qb);
    attn_kernel<<<1024, 256, 0, stream>>>(Qb, K_bf, VT_bf, Oq0, Oq1, Oq2, Oq3, Mq, Lq);
    attn_combine<<<2048, 256, 0, stream>>>(Oq0, Oq1, Oq2, Oq3, Mq, Lq, C1b, AO);
    gemm_nt64<float><<<dim3(32, 16), 256, 0, stream>>>(AO, Wo_bf, out, 2048, 2048, 2048);
}